// Round 12
// baseline (1931.849 us; speedup 1.0000x reference)
//
#include <hip/hip_runtime.h>
#include <cstdint>
#include <cstddef>

typedef _Float16 f16;
typedef __attribute__((ext_vector_type(8))) _Float16 f16x8;
typedef __attribute__((ext_vector_type(4))) _Float16 f16x4;
typedef __attribute__((ext_vector_type(4))) float f32x4;

#define MFMA_F16(a, b, c) __builtin_amdgcn_mfma_f32_16x16x32_f16((a), (b), (c), 0, 0, 0)

#define GL2LDS(gsrc, ldst)                                                  \
    __builtin_amdgcn_global_load_lds(                                        \
        (const __attribute__((address_space(1))) void*)(gsrc),               \
        (__attribute__((address_space(3))) void*)(ldst), 16, 0, 0)

#define WAITV(n) asm volatile("s_waitcnt vmcnt(" #n ")" ::: "memory")
#define BAR() __builtin_amdgcn_s_barrier()
#define PRIO(n) __builtin_amdgcn_s_setprio(n)

#define SWZ(row) (((row) >> 1) & 3)

// ws layout (bytes): [0,1.5M) W_L|W_R|W_out f16 | [1.5M,1.5M+64K) norm partials
//   | [+64K,+68K) flags | [2M,130M) xt (8 blade planes [16384][512] f16)
//   | [130M,258M) gp f16 [b][blade][ch]   (fast k2 path only)

// ---------------------------------------------------------------------------
// k0: blocks 0..8191 transpose x -> xt f16; blocks 8192..9215 convert weights.
// ---------------------------------------------------------------------------
__global__ __launch_bounds__(256) void k0(const float* __restrict__ x,
                                          const float* __restrict__ wl,
                                          const float* __restrict__ wr,
                                          const float* __restrict__ wo,
                                          f16* __restrict__ wdst,
                                          f16* __restrict__ xt) {
    const int bid = blockIdx.x;
    if (bid >= 8192) {
        int i = (bid - 8192) * 256 + threadIdx.x;
        wdst[i]          = (f16)wl[i];
        wdst[262144 + i] = (f16)wr[i];
        wdst[524288 + i] = (f16)wo[i];
        return;
    }
    const int b = (bid >> 1) * 4 + (threadIdx.x >> 6);
    const int m = (bid & 1) * 256 + (threadIdx.x & 63) * 4;
    const float* src = x + ((size_t)b * 512 + m) * 8;
    f32x4 v[8];
#pragma unroll
    for (int u = 0; u < 8; ++u) v[u] = *(const f32x4*)(src + u * 4);
#pragma unroll
    for (int i = 0; i < 8; ++i) {
        f16x4 w;
#pragma unroll
        for (int j = 0; j < 4; ++j) w[j] = (f16)v[j * 2 + (i >> 2)][i & 3];
        *(f16x4*)(xt + (size_t)i * 8388608 + (size_t)b * 512 + m) = w;
    }
}

// ---------------------------------------------------------------------------
// k1 (R8-benched version, 187us): block 32b x (2 side x 128 ch), 512 thr /
// 8 waves; wave = 16b x 32ch both sides, acc[8][4]. BK=32, 3 LDS bufs,
// 2 phases per K-tile (stageA | stageB), waits 6/4/0.
// ---------------------------------------------------------------------------
__global__ __launch_bounds__(512, 2) void k1(
    const f16* __restrict__ xt, const f16* __restrict__ wf,
    const float* __restrict__ bl_p, const float* __restrict__ br_p,
    char* gp_out)
{
    __shared__ __align__(16) f16 AsF[3 * 8192];
    __shared__ __align__(16) f16 BsF[3 * 8192];

    const int L = blockIdx.x;
    const int xcd = L & 7, sl = L >> 3;
    const int bt = xcd * 64 + (sl >> 2), ct = sl & 3;
    const int b0 = bt * 32, n0 = ct * 128;

    const int tid = threadIdx.x, lane = tid & 63, wv = tid >> 6;
    const int wb = wv >> 2, wn = wv & 3;
    const int r_lo = lane & 15, s_hi = lane >> 4;

    const int gA0 = tid, gA1 = tid + 512;
    const int ba0 = gA0 >> 7, ra0 = (gA0 >> 2) & 31, ga0 = (gA0 & 3) ^ SWZ(ra0);
    const int ba1 = gA1 >> 7, ra1 = (gA1 >> 2) & 31, ga1 = (gA1 & 3) ^ SWZ(ra1);
    const f16* aS0 = xt + (size_t)ba0 * 8388608 + (size_t)(b0 + ra0) * 512 + ga0 * 8;
    const f16* aS1 = xt + (size_t)ba1 * 8388608 + (size_t)(b0 + ra1) * 512 + ga1 * 8;
    const int wch = tid >> 2, wg = (tid & 3) ^ SWZ(wch);
    const f16* wS0 = wf + (size_t)(n0 + wch) * 512 + wg * 8;
    const f16* wS1 = wS0 + 262144;

    const int ar = wb * 16 + r_lo;
    const int arow = ar * 32 + ((s_hi ^ SWZ(ar)) << 3);
    int bro[4];
#pragma unroll
    for (int t = 0; t < 4; ++t) {
        const int nrow = ((t & 2) ? 128 : 0) + wn * 32 + (t & 1) * 16 + r_lo;
        bro[t] = nrow * 32 + ((s_hi ^ SWZ(nrow)) << 3);
    }

    f32x4 acc[8][4];
    const f32x4 zero = {0.f, 0.f, 0.f, 0.f};
#pragma unroll
    for (int i = 0; i < 8; ++i)
#pragma unroll
        for (int t = 0; t < 4; ++t) acc[i][t] = zero;

    auto stageA = [&](int kt, int buf) {
        GL2LDS(aS0 + kt * 32, AsF + buf * 8192 + wv * 512);
        GL2LDS(aS1 + kt * 32, AsF + buf * 8192 + 4096 + wv * 512);
    };
    auto stageB = [&](int kt, int buf) {
        GL2LDS(wS0 + kt * 32, BsF + buf * 8192 + wv * 512);
        GL2LDS(wS1 + kt * 32, BsF + buf * 8192 + 4096 + wv * 512);
    };

    stageA(0, 0); stageB(0, 0);
    stageA(1, 1); stageB(1, 1);

#pragma unroll
    for (int kt = 0; kt < 16; ++kt) {
        const int buf = kt % 3, nbuf = (kt + 2) % 3;
        const f16* Ab = AsF + buf * 8192;
        const f16* Bb = BsF + buf * 8192;
        if (kt < 14) stageA(kt + 2, nbuf);
        if (kt <= 13)      { WAITV(6); }
        else if (kt == 14) { WAITV(4); }
        else               { WAITV(0); }
        BAR();
        f16x8 bf[4];
#pragma unroll
        for (int t = 0; t < 4; ++t) bf[t] = *(const f16x8*)(Bb + bro[t]);
        {
            f16x8 a0 = *(const f16x8*)(Ab + 0 * 1024 + arow);
            f16x8 a1 = *(const f16x8*)(Ab + 1 * 1024 + arow);
            f16x8 a2 = *(const f16x8*)(Ab + 2 * 1024 + arow);
            f16x8 a3 = *(const f16x8*)(Ab + 3 * 1024 + arow);
            PRIO(1);
#pragma unroll
            for (int t = 0; t < 4; ++t) {
                acc[0][t] = MFMA_F16(a0, bf[t], acc[0][t]);
                acc[1][t] = MFMA_F16(a1, bf[t], acc[1][t]);
                acc[2][t] = MFMA_F16(a2, bf[t], acc[2][t]);
                acc[3][t] = MFMA_F16(a3, bf[t], acc[3][t]);
            }
            PRIO(0);
        }
        BAR();
        if (kt < 14) stageB(kt + 2, nbuf);
        {
            f16x8 a4 = *(const f16x8*)(Ab + 4 * 1024 + arow);
            f16x8 a5 = *(const f16x8*)(Ab + 5 * 1024 + arow);
            f16x8 a6 = *(const f16x8*)(Ab + 6 * 1024 + arow);
            f16x8 a7 = *(const f16x8*)(Ab + 7 * 1024 + arow);
            PRIO(1);
#pragma unroll
            for (int t = 0; t < 4; ++t) {
                acc[4][t] = MFMA_F16(a4, bf[t], acc[4][t]);
                acc[5][t] = MFMA_F16(a5, bf[t], acc[5][t]);
                acc[6][t] = MFMA_F16(a6, bf[t], acc[6][t]);
                acc[7][t] = MFMA_F16(a7, bf[t], acc[7][t]);
            }
            PRIO(0);
        }
        BAR();
    }

#pragma unroll
    for (int t = 0; t < 2; ++t) {
        const int ch = n0 + wn * 32 + t * 16 + r_lo;
        const float blv = bl_p[ch], brv = br_p[ch];
#pragma unroll
        for (int rr = 0; rr < 4; ++rr) {
            const int b_g = b0 + wb * 16 + s_hi * 4 + rr;
            float Lv[8], Rv[8];
#pragma unroll
            for (int i = 0; i < 8; ++i) { Lv[i] = acc[i][t][rr]; Rv[i] = acc[i][2 + t][rr]; }
            Lv[0] += blv; Rv[0] += brv;
            float g[8];
            g[0] = Lv[0]*Rv[0]+Lv[1]*Rv[1]+Lv[2]*Rv[2]+Lv[3]*Rv[3]-Lv[4]*Rv[4]-Lv[5]*Rv[5]-Lv[6]*Rv[6]-Lv[7]*Rv[7];
            g[1] = Lv[0]*Rv[1]+Lv[1]*Rv[0]-Lv[2]*Rv[4]-Lv[3]*Rv[5]+Lv[4]*Rv[2]+Lv[5]*Rv[3]-Lv[6]*Rv[7]-Lv[7]*Rv[6];
            g[2] = Lv[0]*Rv[2]+Lv[1]*Rv[4]+Lv[2]*Rv[0]-Lv[3]*Rv[6]-Lv[4]*Rv[1]+Lv[5]*Rv[7]+Lv[6]*Rv[3]+Lv[7]*Rv[5];
            g[3] = Lv[0]*Rv[3]+Lv[1]*Rv[5]+Lv[2]*Rv[6]+Lv[3]*Rv[0]-Lv[4]*Rv[7]-Lv[5]*Rv[1]-Lv[6]*Rv[2]-Lv[7]*Rv[4];
            g[4] = Lv[0]*Rv[4]+Lv[1]*Rv[2]-Lv[2]*Rv[1]+Lv[3]*Rv[7]+Lv[4]*Rv[0]-Lv[5]*Rv[6]+Lv[6]*Rv[5]+Lv[7]*Rv[3];
            g[5] = Lv[0]*Rv[5]+Lv[1]*Rv[3]-Lv[2]*Rv[7]-Lv[3]*Rv[1]+Lv[4]*Rv[6]+Lv[5]*Rv[0]-Lv[6]*Rv[4]-Lv[7]*Rv[2];
            g[6] = Lv[0]*Rv[6]+Lv[1]*Rv[7]+Lv[2]*Rv[3]-Lv[3]*Rv[2]-Lv[4]*Rv[5]+Lv[5]*Rv[4]+Lv[6]*Rv[0]+Lv[7]*Rv[1];
            g[7] = Lv[0]*Rv[7]+Lv[1]*Rv[6]-Lv[2]*Rv[5]+Lv[3]*Rv[4]+Lv[4]*Rv[3]-Lv[5]*Rv[2]+Lv[6]*Rv[1]+Lv[7]*Rv[0];
            char* dst = gp_out + (size_t)b_g * 16384 + (size_t)ch * 2;
#pragma unroll
            for (int i = 0; i < 8; ++i) *(f16*)(dst + (size_t)i * 1024) = (f16)g[i];
        }
    }
}

// ---------------------------------------------------------------------------
// k2a (fast path): block = 16b x 256ch (half), 512 thr / 8 waves, wave =
// 16b x 32ch, acc[8][2] (~2 blocks/CU). gp read from ws. Writes UNSCALED out,
// per-batch norm partial via atomicAdd; last sibling (flag) rescales 512ch
// from hot L2. Flags/partials zeroed per call by hipMemsetAsync.
// ---------------------------------------------------------------------------
__global__ __launch_bounds__(512, 2) void k2a(
    const f16* __restrict__ gp, const f16* __restrict__ wo,
    const float* __restrict__ bo_p, const float* __restrict__ an_p,
    float* outp, float* __restrict__ normp, int* __restrict__ flags)
{
    __shared__ __align__(16) f16 AsF[3 * 4096];   // 24KB
    __shared__ float red[16][8];
    __shared__ float totv[16];
    __shared__ int amLast;

    // sibling halves consecutive -> same XCD under round-robin
    const int gid = (blockIdx.x & 7) * 256 + (blockIdx.x >> 3);
    const int bt = gid >> 1, half = gid & 1;
    const int b0 = bt * 16;

    const int tid = threadIdx.x, lane = tid & 63, wv = tid >> 6;  // wv 0..7
    const int r_lo = lane & 15, s_hi = lane >> 4;

    // A staging (1 call, all 512 lanes = 8KB tile)
    const int abl = tid >> 6, arw = (tid >> 2) & 15, agp = (tid & 3) ^ SWZ(arw);
    const f16* aS = gp + (size_t)(b0 + arw) * 8192 + (size_t)abl * 512 + agp * 8;
    f16* aD = AsF + wv * 512;

    const int aoff = r_lo * 32 + ((s_hi ^ SWZ(r_lo)) << 3);

    const int nl0 = half * 256 + wv * 32 + r_lo, nl1 = nl0 + 16;
    const f16* bQ0 = wo + (size_t)nl0 * 512 + s_hi * 8;
    const f16* bQ1 = wo + (size_t)nl1 * 512 + s_hi * 8;

    f32x4 acc[8][2];
    const f32x4 zero = {0.f, 0.f, 0.f, 0.f};
#pragma unroll
    for (int i = 0; i < 8; ++i) { acc[i][0] = zero; acc[i][1] = zero; }

    auto stageA = [&](int kt, int buf) { GL2LDS(aS + kt * 32, aD + buf * 4096); };

    f16x8 bregs[2][2];
    bregs[0][0] = *(const f16x8*)bQ0;
    bregs[0][1] = *(const f16x8*)bQ1;
    stageA(0, 0);
    stageA(1, 1);

#pragma unroll
    for (int kt = 0; kt < 16; ++kt) {
        if (kt < 15) {
            bregs[(kt + 1) & 1][0] = *(const f16x8*)(bQ0 + (kt + 1) * 32);
            bregs[(kt + 1) & 1][1] = *(const f16x8*)(bQ1 + (kt + 1) * 32);
        }
        if (kt + 2 < 16) stageA(kt + 2, (kt + 2) % 3);
        if (kt <= 13)      { WAITV(4); }
        else if (kt == 14) { WAITV(3); }
        else               { WAITV(0); }
        BAR();
        const f16* Ab = AsF + (kt % 3) * 4096;
        const f16x8 b0f = bregs[kt & 1][0];
        const f16x8 b1f = bregs[kt & 1][1];
        {
            f16x8 a0 = *(const f16x8*)(Ab + 0 * 512 + aoff);
            f16x8 a1 = *(const f16x8*)(Ab + 1 * 512 + aoff);
            f16x8 a2 = *(const f16x8*)(Ab + 2 * 512 + aoff);
            f16x8 a3 = *(const f16x8*)(Ab + 3 * 512 + aoff);
            PRIO(1);
            acc[0][0] = MFMA_F16(a0, b0f, acc[0][0]); acc[0][1] = MFMA_F16(a0, b1f, acc[0][1]);
            acc[1][0] = MFMA_F16(a1, b0f, acc[1][0]); acc[1][1] = MFMA_F16(a1, b1f, acc[1][1]);
            acc[2][0] = MFMA_F16(a2, b0f, acc[2][0]); acc[2][1] = MFMA_F16(a2, b1f, acc[2][1]);
            acc[3][0] = MFMA_F16(a3, b0f, acc[3][0]); acc[3][1] = MFMA_F16(a3, b1f, acc[3][1]);
            PRIO(0);
        }
        {
            f16x8 a4 = *(const f16x8*)(Ab + 4 * 512 + aoff);
            f16x8 a5 = *(const f16x8*)(Ab + 5 * 512 + aoff);
            f16x8 a6 = *(const f16x8*)(Ab + 6 * 512 + aoff);
            f16x8 a7 = *(const f16x8*)(Ab + 7 * 512 + aoff);
            PRIO(1);
            acc[4][0] = MFMA_F16(a4, b0f, acc[4][0]); acc[4][1] = MFMA_F16(a4, b1f, acc[4][1]);
            acc[5][0] = MFMA_F16(a5, b0f, acc[5][0]); acc[5][1] = MFMA_F16(a5, b1f, acc[5][1]);
            acc[6][0] = MFMA_F16(a6, b0f, acc[6][0]); acc[6][1] = MFMA_F16(a6, b1f, acc[6][1]);
            acc[7][0] = MFMA_F16(a7, b0f, acc[7][0]); acc[7][1] = MFMA_F16(a7, b1f, acc[7][1]);
            PRIO(0);
        }
        BAR();
    }

    const float bo0 = bo_p[nl0], bo1 = bo_p[nl1];

    // per-batch norm partials over this block's 32ch-per-lane-pair
    float partial[4];
#pragma unroll
    for (int rr = 0; rr < 4; ++rr) {
        float o = acc[0][0][rr] + bo0;
        float ss = o * o;
#pragma unroll
        for (int i = 1; i < 8; ++i) ss += acc[i][0][rr] * acc[i][0][rr];
        float s = sqrtf(ss);
        o = acc[0][1][rr] + bo1;
        ss = o * o;
#pragma unroll
        for (int i = 1; i < 8; ++i) ss += acc[i][1][rr] * acc[i][1][rr];
        partial[rr] = s + sqrtf(ss);
    }
#pragma unroll
    for (int off = 1; off < 16; off <<= 1)
#pragma unroll
        for (int rr = 0; rr < 4; ++rr) partial[rr] += __shfl_xor(partial[rr], off);
    if (r_lo == 0)
#pragma unroll
        for (int rr = 0; rr < 4; ++rr) red[s_hi * 4 + rr][wv] = partial[rr];
    __syncthreads();
    if (tid < 16) {
        float bp = 0.f;
#pragma unroll
        for (int w = 0; w < 8; ++w) bp += red[tid][w];
        atomicAdd(normp + bt * 16 + tid, bp);
    }

    // write UNSCALED out (bias included)
#pragma unroll
    for (int rr = 0; rr < 4; ++rr) {
        const int b_g = b0 + s_hi * 4 + rr;
        float* dst = outp + (size_t)b_g * 4096;
        f32x4 v;
        v[0] = acc[0][0][rr] + bo0;
        v[1] = acc[1][0][rr]; v[2] = acc[2][0][rr]; v[3] = acc[3][0][rr];
        *(f32x4*)(dst + (size_t)nl0 * 8) = v;
        v[0] = acc[4][0][rr]; v[1] = acc[5][0][rr];
        v[2] = acc[6][0][rr]; v[3] = acc[7][0][rr];
        *(f32x4*)(dst + (size_t)nl0 * 8 + 4) = v;
        v[0] = acc[0][1][rr] + bo1;
        v[1] = acc[1][1][rr]; v[2] = acc[2][1][rr]; v[3] = acc[3][1][rr];
        *(f32x4*)(dst + (size_t)nl1 * 8) = v;
        v[0] = acc[4][1][rr]; v[1] = acc[5][1][rr];
        v[2] = acc[6][1][rr]; v[3] = acc[7][1][rr];
        *(f32x4*)(dst + (size_t)nl1 * 8 + 4) = v;
    }

    // release: my stores -> fence -> block sync -> flag
    __threadfence();
    __syncthreads();
    if (tid == 0) {
        int old = atomicAdd(flags + bt, 1);
        amLast = (old == 1);
    }
    __syncthreads();
    if (!amLast) return;

    __threadfence();   // acquire side
    if (tid < 16) totv[tid] = atomicAdd(normp + bt * 16 + tid, 0.0f);  // coherent read
    __syncthreads();

    const int b = tid >> 5, c32 = tid & 31;
    const float inv = 1.0f / (totv[b] * (1.0f / 512.0f) + 1e-6f);
    float* dst = outp + (size_t)(b0 + b) * 4096 + c32 * 128;
    const float* anp = an_p + c32 * 16;
#pragma unroll
    for (int k = 0; k < 16; ++k) {
        const float s = anp[k] * inv;
        f32x4 v0 = *(f32x4*)(dst + k * 8);
        f32x4 v1 = *(f32x4*)(dst + k * 8 + 4);
        v0 *= s; v1 *= s;
        *(f32x4*)(dst + k * 8) = v0;
        *(f32x4*)(dst + k * 8 + 4) = v1;
    }
}

// ---------------------------------------------------------------------------
// k2f (fallback, R8-benched): block 16b x 512ch, 512 thr / 8 waves, wave =
// 16b x 64ch (acc[8][4]), gp in d_out, 3 bufs, 2-phase, waits 7/5/0.
// ---------------------------------------------------------------------------
__global__ __launch_bounds__(512, 2) void k2f(
    const char* gp_in, const f16* __restrict__ wo,
    const float* __restrict__ bo_p, const float* __restrict__ an_p,
    float* outp)
{
    __shared__ __align__(16) f16 AsF[3 * 4096];
    __shared__ __align__(16) f16 BsF[3 * 16384];
    __shared__ float red[16][8];

    const int b0 = blockIdx.x * 16;
    const int tid = threadIdx.x, lane = tid & 63, wv = tid >> 6;
    const int r_lo = lane & 15, s_hi = lane >> 4;

    const int abl = tid >> 6, arw = (tid >> 2) & 15, agp = (tid & 3) ^ SWZ(arw);
    const char* aS = gp_in + (size_t)(b0 + arw) * 16384 + (size_t)abl * 1024 + agp * 16;
    const f16* bS[4];
#pragma unroll
    for (int j = 0; j < 4; ++j) {
        const int n = j * 128 + (tid >> 2);
        bS[j] = wo + (size_t)n * 512 + ((tid & 3) ^ SWZ(n)) * 8;
    }

    const int aoff = r_lo * 32 + ((s_hi ^ SWZ(r_lo)) << 3);
    int bro[4];
#pragma unroll
    for (int t = 0; t < 4; ++t) {
        const int nrow = wv * 64 + t * 16 + r_lo;
        bro[t] = nrow * 32 + ((s_hi ^ SWZ(nrow)) << 3);
    }

    f32x4 acc[8][4];
    const f32x4 zero = {0.f, 0.f, 0.f, 0.f};
#pragma unroll
    for (int i = 0; i < 8; ++i)
#pragma unroll
        for (int t = 0; t < 4; ++t) acc[i][t] = zero;

    auto stageB01 = [&](int kt, int buf) {
        GL2LDS(bS[0] + kt * 32, BsF + buf * 16384 + 0 * 4096 + wv * 512);
        GL2LDS(bS[1] + kt * 32, BsF + buf * 16384 + 1 * 4096 + wv * 512);
    };
    auto stageAB23 = [&](int kt, int buf) {
        GL2LDS(aS + kt * 64, AsF + buf * 4096 + wv * 512);
        GL2LDS(bS[2] + kt * 32, BsF + buf * 16384 + 2 * 4096 + wv * 512);
        GL2LDS(bS[3] + kt * 32, BsF + buf * 16384 + 3 * 4096 + wv * 512);
    };

    stageB01(0, 0); stageAB23(0, 0);
    stageB01(1, 1); stageAB23(1, 1);

#pragma unroll
    for (int kt = 0; kt < 16; ++kt) {
        const int buf = kt % 3, nbuf = (kt + 2) % 3;
        const f16* Ab = AsF + buf * 4096;
        const f16* Bb = BsF + buf * 16384;
        if (kt < 14) stageB01(kt + 2, nbuf);
        if (kt <= 13)      { WAITV(7); }
        else if (kt == 14) { WAITV(5); }
        else               { WAITV(0); }
        BAR();
        f16x8 af[8];
#pragma unroll
        for (int i = 0; i < 8; ++i) af[i] = *(const f16x8*)(Ab + i * 512 + aoff);
        {
            f16x8 b0f = *(const f16x8*)(Bb + bro[0]);
            f16x8 b1f = *(const f16x8*)(Bb + bro[1]);
            PRIO(1);
#pragma unroll
            for (int i = 0; i < 8; ++i) {
                acc[i][0] = MFMA_F16(af[i], b0f, acc[i][0]);
                acc[i][1] = MFMA_F16(af[i], b1f, acc[i][1]);
            }
            PRIO(0);
        }
        BAR();
        if (kt < 14) stageAB23(kt + 2, nbuf);
        {
            f16x8 b2f = *(const f16x8*)(Bb + bro[2]);
            f16x8 b3f = *(const f16x8*)(Bb + bro[3]);
            PRIO(1);
#pragma unroll
            for (int i = 0; i < 8; ++i) {
                acc[i][2] = MFMA_F16(af[i], b2f, acc[i][2]);
                acc[i][3] = MFMA_F16(af[i], b3f, acc[i][3]);
            }
            PRIO(0);
        }
        BAR();
    }

    float bo_t[4], an_t[4];
#pragma unroll
    for (int t = 0; t < 4; ++t) {
        const int c = wv * 64 + t * 16 + r_lo;
        bo_t[t] = bo_p[c]; an_t[t] = an_p[c];
    }

    float partial[4];
#pragma unroll
    for (int rr = 0; rr < 4; ++rr) {
        float sum = 0.f;
#pragma unroll
        for (int t = 0; t < 4; ++t) {
            float o = acc[0][t][rr] + bo_t[t];
            float ss = o * o;
#pragma unroll
            for (int i = 1; i < 8; ++i) ss += acc[i][t][rr] * acc[i][t][rr];
            sum += sqrtf(ss);
        }
        partial[rr] = sum;
    }
#pragma unroll
    for (int off = 1; off < 16; off <<= 1)
#pragma unroll
        for (int rr = 0; rr < 4; ++rr) partial[rr] += __shfl_xor(partial[rr], off);
    if (r_lo == 0)
#pragma unroll
        for (int rr = 0; rr < 4; ++rr) red[s_hi * 4 + rr][wv] = partial[rr];
    __syncthreads();

#pragma unroll
    for (int rr = 0; rr < 4; ++rr) {
        float tot = 0.f;
#pragma unroll
        for (int w = 0; w < 8; ++w) tot += red[s_hi * 4 + rr][w];
        const float inv = 1.0f / (tot * (1.0f / 512.0f) + 1e-6f);
        const int b_g = b0 + s_hi * 4 + rr;
        float* dst = outp + (size_t)b_g * 4096;
#pragma unroll
        for (int t = 0; t < 4; ++t) {
            const float sc = an_t[t] * inv;
            const int c = wv * 64 + t * 16 + r_lo;
            f32x4 v0, v1;
            v0[0] = (acc[0][t][rr] + bo_t[t]) * sc;
            v0[1] = acc[1][t][rr] * sc; v0[2] = acc[2][t][rr] * sc; v0[3] = acc[3][t][rr] * sc;
            v1[0] = acc[4][t][rr] * sc; v1[1] = acc[5][t][rr] * sc;
            v1[2] = acc[6][t][rr] * sc; v1[3] = acc[7][t][rr] * sc;
            *(f32x4*)(dst + (size_t)c * 8) = v0;
            *(f32x4*)(dst + (size_t)c * 8 + 4) = v1;
        }
    }
}

// ---------------------------------------------------------------------------
extern "C" void kernel_launch(void* const* d_in, const int* in_sizes, int n_in,
                              void* d_out, int out_size, void* d_ws, size_t ws_size,
                              hipStream_t stream) {
    const float* x  = (const float*)d_in[0];
    const float* wl = (const float*)d_in[1];
    const float* bl = (const float*)d_in[2];
    const float* wr = (const float*)d_in[3];
    const float* br = (const float*)d_in[4];
    const float* wo = (const float*)d_in[5];
    const float* bo = (const float*)d_in[6];
    const float* an = (const float*)d_in[7];
    char* wsb = (char*)d_ws;
    f16* wf = (f16*)d_ws;
    f16* xt = wf + (1 << 20);                        // byte 2MB
    const size_t GPOFF = (size_t)130 * 1024 * 1024;  // gp at byte 130MB
    const size_t NEED  = GPOFF + (size_t)128 * 1024 * 1024;

    hipLaunchKernelGGL(k0, dim3(9216), dim3(256), 0, stream, x, wl, wr, wo, wf, xt);

    if (ws_size >= NEED) {
        f16* gp = (f16*)(wsb + GPOFF);
        float* normp = (float*)(wsb + 0x180000);
        int* flags = (int*)(wsb + 0x180000 + 65536);
        hipMemsetAsync(wsb + 0x180000, 0, 65536 + 4096, stream);
        hipLaunchKernelGGL(k1, dim3(2048), dim3(512), 0, stream, xt, wf, bl, br, (char*)gp);
        hipLaunchKernelGGL(k2a, dim3(2048), dim3(512), 0, stream,
                           gp, wf + 524288, bo, an, (float*)d_out, normp, flags);
    } else {
        hipLaunchKernelGGL(k1, dim3(2048), dim3(512), 0, stream, xt, wf, bl, br, (char*)d_out);
        hipLaunchKernelGGL(k2f, dim3(1024), dim3(512), 0, stream,
                           (const char*)d_out, wf + 524288, bo, an, (float*)d_out);
    }
}

// Round 13
// 489.025 us; speedup vs baseline: 3.9504x; 3.9504x over previous
//
#include <hip/hip_runtime.h>
#include <cstdint>
#include <cstddef>

typedef _Float16 f16;
typedef __attribute__((ext_vector_type(8))) _Float16 f16x8;
typedef __attribute__((ext_vector_type(4))) _Float16 f16x4;
typedef __attribute__((ext_vector_type(4))) float f32x4;

#define MFMA_F16(a, b, c) __builtin_amdgcn_mfma_f32_16x16x32_f16((a), (b), (c), 0, 0, 0)

#define GL2LDS(gsrc, ldst)                                                  \
    __builtin_amdgcn_global_load_lds(                                        \
        (const __attribute__((address_space(1))) void*)(gsrc),               \
        (__attribute__((address_space(3))) void*)(ldst), 16, 0, 0)

#define WAITV(n) asm volatile("s_waitcnt vmcnt(" #n ")" ::: "memory")
#define BAR() __builtin_amdgcn_s_barrier()
#define PRIO(n) __builtin_amdgcn_s_setprio(n)

#define SWZ(row) (((row) >> 1) & 3)

// ws layout (f16 elems): [0,262144) W_L | [262144,524288) W_R |
//   [524288,786432) W_out | xt at elem 1<<20: 8 blade planes [16384][512].
// gp (f16) in d_out: batch b at byte b*16384, blade i at +i*1024, ch n at +2n.
//
// SAFETY: LDS staging at TOP of iteration, 3 buffers (R9 lesson).
// FIFO: B-reg loads issued BEFORE stages each iteration (R10 lesson).
// NEW (R12 lesson applied): k1 sized for 2 blocks/CU (48KB LDS, <=128 VGPR)
// so independent barrier groups supply the latency hiding.

// ---------------------------------------------------------------------------
// k0: blocks 0..8191 transpose x -> xt f16; blocks 8192..9215 convert weights.
// ---------------------------------------------------------------------------
__global__ __launch_bounds__(256) void k0(const float* __restrict__ x,
                                          const float* __restrict__ wl,
                                          const float* __restrict__ wr,
                                          const float* __restrict__ wo,
                                          f16* __restrict__ wdst,
                                          f16* __restrict__ xt) {
    const int bid = blockIdx.x;
    if (bid >= 8192) {
        int i = (bid - 8192) * 256 + threadIdx.x;
        wdst[i]          = (f16)wl[i];
        wdst[262144 + i] = (f16)wr[i];
        wdst[524288 + i] = (f16)wo[i];
        return;
    }
    const int b = (bid >> 1) * 4 + (threadIdx.x >> 6);
    const int m = (bid & 1) * 256 + (threadIdx.x & 63) * 4;
    const float* src = x + ((size_t)b * 512 + m) * 8;
    f32x4 v[8];
#pragma unroll
    for (int u = 0; u < 8; ++u) v[u] = *(const f32x4*)(src + u * 4);
#pragma unroll
    for (int i = 0; i < 8; ++i) {
        f16x4 w;
#pragma unroll
        for (int j = 0; j < 4; ++j) w[j] = (f16)v[j * 2 + (i >> 2)][i & 3];
        *(f16x4*)(xt + (size_t)i * 8388608 + (size_t)b * 512 + m) = w;
    }
}

// ---------------------------------------------------------------------------
// k1: vec_L/vec_R GEMMs + geometric product.
// Block 32 b x 64 ch, 512 thr / 8 waves (wb2 x wn4); wave = 16b x 16ch BOTH
// sides, acc[8][2] = 64 regs. A staged global_load_lds (2 calls/tile, 3 bufs
// = 48KB -> 2 blocks/CU); B (L2-resident W) direct global->reg, bregs[kt&1].
// Issue order: B(kt+1) x2 first, then stageA(kt+2) x2. Waits 6/4/0.
// ---------------------------------------------------------------------------
__global__ __launch_bounds__(512, 4) void k1(
    const f16* __restrict__ xt, const f16* __restrict__ wf,
    const float* __restrict__ bl_p, const float* __restrict__ br_p,
    char* gp_out)
{
    __shared__ __align__(16) f16 AsF[3 * 8192];   // [buf][blade8][bat32][k32] 48KB

    const int L = blockIdx.x;                     // 0..4095, XCD-chunked
    const int xcd = L & 7, sl = L >> 3;           // sl 0..511
    const int bt = xcd * 64 + (sl >> 3), ct = sl & 7;
    const int b0 = bt * 32, n0 = ct * 64;

    const int tid = threadIdx.x, lane = tid & 63, wv = tid >> 6;  // wv 0..7
    const int wb = wv >> 2, wn = wv & 3;
    const int r_lo = lane & 15, s_hi = lane >> 4;

    // A staging sources (2 calls x 512 lanes = 16KB tile; swizzle keyed on bat)
    const int gA0 = tid, gA1 = tid + 512;
    const int ba0 = gA0 >> 7, ra0 = (gA0 >> 2) & 31, ga0 = (gA0 & 3) ^ SWZ(ra0);
    const int ba1 = gA1 >> 7, ra1 = (gA1 >> 2) & 31, ga1 = (gA1 & 3) ^ SWZ(ra1);
    const f16* aS0 = xt + (size_t)ba0 * 8388608 + (size_t)(b0 + ra0) * 512 + ga0 * 8;
    const f16* aS1 = xt + (size_t)ba1 * 8388608 + (size_t)(b0 + ra1) * 512 + ga1 * 8;

    // A compute-side LDS offset
    const int ar = wb * 16 + r_lo;
    const int arow = ar * 32 + ((s_hi ^ SWZ(ar)) << 3);   // + blade*1024 + buf*8192

    // B direct pointers (this wave's 16-ch strip, both sides)
    const int chrow = n0 + wn * 16 + r_lo;
    const f16* bPL = wf + (size_t)chrow * 512 + s_hi * 8;
    const f16* bPR = bPL + 262144;

    f32x4 acc[8][2];
    const f32x4 zero = {0.f, 0.f, 0.f, 0.f};
#pragma unroll
    for (int i = 0; i < 8; ++i) { acc[i][0] = zero; acc[i][1] = zero; }

    auto stageA = [&](int kt, int buf) {
        GL2LDS(aS0 + kt * 32, AsF + buf * 8192 + wv * 512);
        GL2LDS(aS1 + kt * 32, AsF + buf * 8192 + 4096 + wv * 512);
    };

    f16x8 bregs[2][2];    // [tile parity][side], statically indexed
    // prologue, FIFO = steady pattern: B first, then stages
    bregs[0][0] = *(const f16x8*)bPL;
    bregs[0][1] = *(const f16x8*)bPR;
    stageA(0, 0);
    stageA(1, 1);

#pragma unroll
    for (int kt = 0; kt < 16; ++kt) {
        if (kt < 15) {
            bregs[(kt + 1) & 1][0] = *(const f16x8*)(bPL + (kt + 1) * 32);
            bregs[(kt + 1) & 1][1] = *(const f16x8*)(bPR + (kt + 1) * 32);
        }
        if (kt + 2 < 16) stageA(kt + 2, (kt + 2) % 3);
        if (kt <= 13)      { WAITV(6); }
        else if (kt == 14) { WAITV(4); }
        else               { WAITV(0); }
        BAR();
        const f16* Ab = AsF + (kt % 3) * 8192;
        const f16x8 bL = bregs[kt & 1][0];
        const f16x8 bR = bregs[kt & 1][1];
        {   // blades 0-3
            f16x8 a0 = *(const f16x8*)(Ab + 0 * 1024 + arow);
            f16x8 a1 = *(const f16x8*)(Ab + 1 * 1024 + arow);
            f16x8 a2 = *(const f16x8*)(Ab + 2 * 1024 + arow);
            f16x8 a3 = *(const f16x8*)(Ab + 3 * 1024 + arow);
            PRIO(1);
            acc[0][0] = MFMA_F16(a0, bL, acc[0][0]); acc[0][1] = MFMA_F16(a0, bR, acc[0][1]);
            acc[1][0] = MFMA_F16(a1, bL, acc[1][0]); acc[1][1] = MFMA_F16(a1, bR, acc[1][1]);
            acc[2][0] = MFMA_F16(a2, bL, acc[2][0]); acc[2][1] = MFMA_F16(a2, bR, acc[2][1]);
            acc[3][0] = MFMA_F16(a3, bL, acc[3][0]); acc[3][1] = MFMA_F16(a3, bR, acc[3][1]);
            PRIO(0);
        }
        {   // blades 4-7
            f16x8 a4 = *(const f16x8*)(Ab + 4 * 1024 + arow);
            f16x8 a5 = *(const f16x8*)(Ab + 5 * 1024 + arow);
            f16x8 a6 = *(const f16x8*)(Ab + 6 * 1024 + arow);
            f16x8 a7 = *(const f16x8*)(Ab + 7 * 1024 + arow);
            PRIO(1);
            acc[4][0] = MFMA_F16(a4, bL, acc[4][0]); acc[4][1] = MFMA_F16(a4, bR, acc[4][1]);
            acc[5][0] = MFMA_F16(a5, bL, acc[5][0]); acc[5][1] = MFMA_F16(a5, bR, acc[5][1]);
            acc[6][0] = MFMA_F16(a6, bL, acc[6][0]); acc[6][1] = MFMA_F16(a6, bR, acc[6][1]);
            acc[7][0] = MFMA_F16(a7, bL, acc[7][0]); acc[7][1] = MFMA_F16(a7, bR, acc[7][1]);
            PRIO(0);
        }
        BAR();
    }

    // epilogue: bias + Cl(3,0) geometric product -> gp f16 in d_out
    const float blv = bl_p[chrow], brv = br_p[chrow];
#pragma unroll
    for (int rr = 0; rr < 4; ++rr) {
        const int b_g = b0 + wb * 16 + s_hi * 4 + rr;
        float Lv[8], Rv[8];
#pragma unroll
        for (int i = 0; i < 8; ++i) { Lv[i] = acc[i][0][rr]; Rv[i] = acc[i][1][rr]; }
        Lv[0] += blv; Rv[0] += brv;
        float g[8];
        g[0] = Lv[0]*Rv[0]+Lv[1]*Rv[1]+Lv[2]*Rv[2]+Lv[3]*Rv[3]-Lv[4]*Rv[4]-Lv[5]*Rv[5]-Lv[6]*Rv[6]-Lv[7]*Rv[7];
        g[1] = Lv[0]*Rv[1]+Lv[1]*Rv[0]-Lv[2]*Rv[4]-Lv[3]*Rv[5]+Lv[4]*Rv[2]+Lv[5]*Rv[3]-Lv[6]*Rv[7]-Lv[7]*Rv[6];
        g[2] = Lv[0]*Rv[2]+Lv[1]*Rv[4]+Lv[2]*Rv[0]-Lv[3]*Rv[6]-Lv[4]*Rv[1]+Lv[5]*Rv[7]+Lv[6]*Rv[3]+Lv[7]*Rv[5];
        g[3] = Lv[0]*Rv[3]+Lv[1]*Rv[5]+Lv[2]*Rv[6]+Lv[3]*Rv[0]-Lv[4]*Rv[7]-Lv[5]*Rv[1]-Lv[6]*Rv[2]-Lv[7]*Rv[4];
        g[4] = Lv[0]*Rv[4]+Lv[1]*Rv[2]-Lv[2]*Rv[1]+Lv[3]*Rv[7]+Lv[4]*Rv[0]-Lv[5]*Rv[6]+Lv[6]*Rv[5]+Lv[7]*Rv[3];
        g[5] = Lv[0]*Rv[5]+Lv[1]*Rv[3]-Lv[2]*Rv[7]-Lv[3]*Rv[1]+Lv[4]*Rv[6]+Lv[5]*Rv[0]-Lv[6]*Rv[4]-Lv[7]*Rv[2];
        g[6] = Lv[0]*Rv[6]+Lv[1]*Rv[7]+Lv[2]*Rv[3]-Lv[3]*Rv[2]-Lv[4]*Rv[5]+Lv[5]*Rv[4]+Lv[6]*Rv[0]+Lv[7]*Rv[1];
        g[7] = Lv[0]*Rv[7]+Lv[1]*Rv[6]-Lv[2]*Rv[5]+Lv[3]*Rv[4]+Lv[4]*Rv[3]-Lv[5]*Rv[2]+Lv[6]*Rv[1]+Lv[7]*Rv[0];
        char* dst = gp_out + (size_t)b_g * 16384 + (size_t)chrow * 2;
#pragma unroll
        for (int i = 0; i < 8; ++i) *(f16*)(dst + (size_t)i * 1024) = (f16)g[i];
    }
}

// ---------------------------------------------------------------------------
// k2 (R8-proven): block 16b x 512ch (norm intra-block), 512 thr / 8 waves,
// wave = 16b x 64ch (acc[8][4]); gp from d_out, 3 bufs, 2-phase, waits 7/5/0.
// Reads gp only from its own batch regions; overwrites them fp32 after.
// ---------------------------------------------------------------------------
__global__ __launch_bounds__(512, 2) void k2(
    const char* gp_in, const f16* __restrict__ wo,
    const float* __restrict__ bo_p, const float* __restrict__ an_p,
    float* outp)
{
    __shared__ __align__(16) f16 AsF[3 * 4096];
    __shared__ __align__(16) f16 BsF[3 * 16384];
    __shared__ float red[16][8];

    const int b0 = blockIdx.x * 16;
    const int tid = threadIdx.x, lane = tid & 63, wv = tid >> 6;
    const int r_lo = lane & 15, s_hi = lane >> 4;

    const int abl = tid >> 6, arw = (tid >> 2) & 15, agp = (tid & 3) ^ SWZ(arw);
    const char* aS = gp_in + (size_t)(b0 + arw) * 16384 + (size_t)abl * 1024 + agp * 16;
    const f16* bS[4];
#pragma unroll
    for (int j = 0; j < 4; ++j) {
        const int n = j * 128 + (tid >> 2);
        bS[j] = wo + (size_t)n * 512 + ((tid & 3) ^ SWZ(n)) * 8;
    }

    const int aoff = r_lo * 32 + ((s_hi ^ SWZ(r_lo)) << 3);
    int bro[4];
#pragma unroll
    for (int t = 0; t < 4; ++t) {
        const int nrow = wv * 64 + t * 16 + r_lo;
        bro[t] = nrow * 32 + ((s_hi ^ SWZ(nrow)) << 3);
    }

    f32x4 acc[8][4];
    const f32x4 zero = {0.f, 0.f, 0.f, 0.f};
#pragma unroll
    for (int i = 0; i < 8; ++i)
#pragma unroll
        for (int t = 0; t < 4; ++t) acc[i][t] = zero;

    auto stageB01 = [&](int kt, int buf) {
        GL2LDS(bS[0] + kt * 32, BsF + buf * 16384 + 0 * 4096 + wv * 512);
        GL2LDS(bS[1] + kt * 32, BsF + buf * 16384 + 1 * 4096 + wv * 512);
    };
    auto stageAB23 = [&](int kt, int buf) {
        GL2LDS(aS + kt * 64, AsF + buf * 4096 + wv * 512);
        GL2LDS(bS[2] + kt * 32, BsF + buf * 16384 + 2 * 4096 + wv * 512);
        GL2LDS(bS[3] + kt * 32, BsF + buf * 16384 + 3 * 4096 + wv * 512);
    };

    stageB01(0, 0); stageAB23(0, 0);
    stageB01(1, 1); stageAB23(1, 1);

#pragma unroll
    for (int kt = 0; kt < 16; ++kt) {
        const int buf = kt % 3, nbuf = (kt + 2) % 3;
        const f16* Ab = AsF + buf * 4096;
        const f16* Bb = BsF + buf * 16384;
        if (kt < 14) stageB01(kt + 2, nbuf);
        if (kt <= 13)      { WAITV(7); }
        else if (kt == 14) { WAITV(5); }
        else               { WAITV(0); }
        BAR();
        f16x8 af[8];
#pragma unroll
        for (int i = 0; i < 8; ++i) af[i] = *(const f16x8*)(Ab + i * 512 + aoff);
        {
            f16x8 b0f = *(const f16x8*)(Bb + bro[0]);
            f16x8 b1f = *(const f16x8*)(Bb + bro[1]);
            PRIO(1);
#pragma unroll
            for (int i = 0; i < 8; ++i) {
                acc[i][0] = MFMA_F16(af[i], b0f, acc[i][0]);
                acc[i][1] = MFMA_F16(af[i], b1f, acc[i][1]);
            }
            PRIO(0);
        }
        BAR();
        if (kt < 14) stageAB23(kt + 2, nbuf);
        {
            f16x8 b2f = *(const f16x8*)(Bb + bro[2]);
            f16x8 b3f = *(const f16x8*)(Bb + bro[3]);
            PRIO(1);
#pragma unroll
            for (int i = 0; i < 8; ++i) {
                acc[i][2] = MFMA_F16(af[i], b2f, acc[i][2]);
                acc[i][3] = MFMA_F16(af[i], b3f, acc[i][3]);
            }
            PRIO(0);
        }
        BAR();
    }

    float bo_t[4], an_t[4];
#pragma unroll
    for (int t = 0; t < 4; ++t) {
        const int c = wv * 64 + t * 16 + r_lo;
        bo_t[t] = bo_p[c]; an_t[t] = an_p[c];
    }

    float partial[4];
#pragma unroll
    for (int rr = 0; rr < 4; ++rr) {
        float sum = 0.f;
#pragma unroll
        for (int t = 0; t < 4; ++t) {
            float o = acc[0][t][rr] + bo_t[t];
            float ss = o * o;
#pragma unroll
            for (int i = 1; i < 8; ++i) ss += acc[i][t][rr] * acc[i][t][rr];
            sum += sqrtf(ss);
        }
        partial[rr] = sum;
    }
#pragma unroll
    for (int off = 1; off < 16; off <<= 1)
#pragma unroll
        for (int rr = 0; rr < 4; ++rr) partial[rr] += __shfl_xor(partial[rr], off);
    if (r_lo == 0)
#pragma unroll
        for (int rr = 0; rr < 4; ++rr) red[s_hi * 4 + rr][wv] = partial[rr];
    __syncthreads();

#pragma unroll
    for (int rr = 0; rr < 4; ++rr) {
        float tot = 0.f;
#pragma unroll
        for (int w = 0; w < 8; ++w) tot += red[s_hi * 4 + rr][w];
        const float inv = 1.0f / (tot * (1.0f / 512.0f) + 1e-6f);
        const int b_g = b0 + s_hi * 4 + rr;
        float* dst = outp + (size_t)b_g * 4096;
#pragma unroll
        for (int t = 0; t < 4; ++t) {
            const float sc = an_t[t] * inv;
            const int c = wv * 64 + t * 16 + r_lo;
            f32x4 v0, v1;
            v0[0] = (acc[0][t][rr] + bo_t[t]) * sc;
            v0[1] = acc[1][t][rr] * sc; v0[2] = acc[2][t][rr] * sc; v0[3] = acc[3][t][rr] * sc;
            v1[0] = acc[4][t][rr] * sc; v1[1] = acc[5][t][rr] * sc;
            v1[2] = acc[6][t][rr] * sc; v1[3] = acc[7][t][rr] * sc;
            *(f32x4*)(dst + (size_t)c * 8) = v0;
            *(f32x4*)(dst + (size_t)c * 8 + 4) = v1;
        }
    }
}

// ---------------------------------------------------------------------------
extern "C" void kernel_launch(void* const* d_in, const int* in_sizes, int n_in,
                              void* d_out, int out_size, void* d_ws, size_t ws_size,
                              hipStream_t stream) {
    const float* x  = (const float*)d_in[0];
    const float* wl = (const float*)d_in[1];
    const float* bl = (const float*)d_in[2];
    const float* wr = (const float*)d_in[3];
    const float* br = (const float*)d_in[4];
    const float* wo = (const float*)d_in[5];
    const float* bo = (const float*)d_in[6];
    const float* an = (const float*)d_in[7];
    f16* wf = (f16*)d_ws;
    f16* xt = wf + (1 << 20);   // byte offset 2MB

    hipLaunchKernelGGL(k0, dim3(9216), dim3(256), 0, stream, x, wl, wr, wo, wf, xt);
    hipLaunchKernelGGL(k1, dim3(4096), dim3(512), 0, stream, xt, wf, bl, br, (char*)d_out);
    hipLaunchKernelGGL(k2, dim3(1024), dim3(512), 0, stream,
                       (const char*)d_out, wf + 524288, bo, an, (float*)d_out);
}

// Round 14
// 407.554 us; speedup vs baseline: 4.7401x; 1.1999x over previous
//
#include <hip/hip_runtime.h>
#include <cstdint>
#include <cstddef>

typedef _Float16 f16;
typedef __attribute__((ext_vector_type(8))) _Float16 f16x8;
typedef __attribute__((ext_vector_type(4))) _Float16 f16x4;
typedef __attribute__((ext_vector_type(4))) float f32x4;

#define MFMA_F16(a, b, c) __builtin_amdgcn_mfma_f32_16x16x32_f16((a), (b), (c), 0, 0, 0)

#define GL2LDS(gsrc, ldst)                                                  \
    __builtin_amdgcn_global_load_lds(                                        \
        (const __attribute__((address_space(1))) void*)(gsrc),               \
        (__attribute__((address_space(3))) void*)(ldst), 16, 0, 0)

#define WAITV(n) asm volatile("s_waitcnt vmcnt(" #n ")" ::: "memory")
#define BAR() __builtin_amdgcn_s_barrier()
#define PRIO(n) __builtin_amdgcn_s_setprio(n)

#define SWZ(row) (((row) >> 1) & 3)

// ws layout (f16 elems): [0,262144) W_L | [262144,524288) W_R |
//   [524288,786432) W_out | xt at elem 1<<20: 8 blade planes [16384][512].
// gp (f16) in d_out: batch b at byte b*16384, blade i at +i*1024, ch n at +2n.
//
// MODEL (validated R8/R10/R11/R13): MfmaUtil ~ MFMA-cyc / LDS-read-cyc.
// Blade-fused GP forces every wave to read 8 A-planes; wave ch-width is
// capped by acc regs (acc[8][4]=128 + ~104 arch = 8 waves/CU). R8's config
// is the Pareto point: 12 ds_read_b128 / 32 MFMA / wave-K-tile, 31.5% util,
// 187us. This file restores that measured optimum exactly.

// ---------------------------------------------------------------------------
// k0: blocks 0..8191 transpose x -> xt f16; blocks 8192..9215 convert weights.
// ---------------------------------------------------------------------------
__global__ __launch_bounds__(256) void k0(const float* __restrict__ x,
                                          const float* __restrict__ wl,
                                          const float* __restrict__ wr,
                                          const float* __restrict__ wo,
                                          f16* __restrict__ wdst,
                                          f16* __restrict__ xt) {
    const int bid = blockIdx.x;
    if (bid >= 8192) {
        int i = (bid - 8192) * 256 + threadIdx.x;
        wdst[i]          = (f16)wl[i];
        wdst[262144 + i] = (f16)wr[i];
        wdst[524288 + i] = (f16)wo[i];
        return;
    }
    const int b = (bid >> 1) * 4 + (threadIdx.x >> 6);
    const int m = (bid & 1) * 256 + (threadIdx.x & 63) * 4;
    const float* src = x + ((size_t)b * 512 + m) * 8;
    f32x4 v[8];
#pragma unroll
    for (int u = 0; u < 8; ++u) v[u] = *(const f32x4*)(src + u * 4);
#pragma unroll
    for (int i = 0; i < 8; ++i) {
        f16x4 w;
#pragma unroll
        for (int j = 0; j < 4; ++j) w[j] = (f16)v[j * 2 + (i >> 2)][i & 3];
        *(f16x4*)(xt + (size_t)i * 8388608 + (size_t)b * 512 + m) = w;
    }
}

// ---------------------------------------------------------------------------
// k1 (R8-benched, 187us): block 32b x (2 side x 128 ch), 512 thr / 8 waves
// (wb2 x wn4); wave = 16b x 32ch both sides, acc[8][4]. BK=32, 3 LDS bufs,
// 2 phases per K-tile (stageA | stageB), waits 6/4/0.
// ---------------------------------------------------------------------------
__global__ __launch_bounds__(512, 2) void k1(
    const f16* __restrict__ xt, const f16* __restrict__ wf,
    const float* __restrict__ bl_p, const float* __restrict__ br_p,
    char* gp_out)
{
    __shared__ __align__(16) f16 AsF[3 * 8192];   // [buf][blade8][bat32][k32] 48KB
    __shared__ __align__(16) f16 BsF[3 * 8192];   // [buf][side2][ch128][k32]  48KB

    const int L = blockIdx.x;                     // 0..2047, XCD-chunked
    const int xcd = L & 7, sl = L >> 3;
    const int bt = xcd * 64 + (sl >> 2), ct = sl & 3;
    const int b0 = bt * 32, n0 = ct * 128;

    const int tid = threadIdx.x, lane = tid & 63, wv = tid >> 6;  // wv 0..7
    const int wb = wv >> 2, wn = wv & 3;
    const int r_lo = lane & 15, s_hi = lane >> 4;

    // A staging sources (2 calls x 512 lanes; swizzle keyed on bat)
    const int gA0 = tid, gA1 = tid + 512;
    const int ba0 = gA0 >> 7, ra0 = (gA0 >> 2) & 31, ga0 = (gA0 & 3) ^ SWZ(ra0);
    const int ba1 = gA1 >> 7, ra1 = (gA1 >> 2) & 31, ga1 = (gA1 & 3) ^ SWZ(ra1);
    const f16* aS0 = xt + (size_t)ba0 * 8388608 + (size_t)(b0 + ra0) * 512 + ga0 * 8;
    const f16* aS1 = xt + (size_t)ba1 * 8388608 + (size_t)(b0 + ra1) * 512 + ga1 * 8;
    // B staging sources (2 calls = side L / side R; swizzle keyed on ch)
    const int wch = tid >> 2, wg = (tid & 3) ^ SWZ(wch);
    const f16* wS0 = wf + (size_t)(n0 + wch) * 512 + wg * 8;
    const f16* wS1 = wS0 + 262144;

    // compute-side offsets
    const int ar = wb * 16 + r_lo;
    const int arow = ar * 32 + ((s_hi ^ SWZ(ar)) << 3);   // + blade*1024
    int bro[4];                                           // L0,L1,R0,R1
#pragma unroll
    for (int t = 0; t < 4; ++t) {
        const int nrow = ((t & 2) ? 128 : 0) + wn * 32 + (t & 1) * 16 + r_lo;
        bro[t] = nrow * 32 + ((s_hi ^ SWZ(nrow)) << 3);
    }

    f32x4 acc[8][4];
    const f32x4 zero = {0.f, 0.f, 0.f, 0.f};
#pragma unroll
    for (int i = 0; i < 8; ++i)
#pragma unroll
        for (int t = 0; t < 4; ++t) acc[i][t] = zero;

    auto stageA = [&](int kt, int buf) {
        GL2LDS(aS0 + kt * 32, AsF + buf * 8192 + wv * 512);
        GL2LDS(aS1 + kt * 32, AsF + buf * 8192 + 4096 + wv * 512);
    };
    auto stageB = [&](int kt, int buf) {
        GL2LDS(wS0 + kt * 32, BsF + buf * 8192 + wv * 512);
        GL2LDS(wS1 + kt * 32, BsF + buf * 8192 + 4096 + wv * 512);
    };

    stageA(0, 0); stageB(0, 0);
    stageA(1, 1); stageB(1, 1);

#pragma unroll
    for (int kt = 0; kt < 16; ++kt) {
        const int buf = kt % 3, nbuf = (kt + 2) % 3;
        const f16* Ab = AsF + buf * 8192;
        const f16* Bb = BsF + buf * 8192;
        // ---------- phase 0 ----------
        if (kt < 14) stageA(kt + 2, nbuf);
        if (kt <= 13)      { WAITV(6); }
        else if (kt == 14) { WAITV(4); }
        else               { WAITV(0); }
        BAR();
        f16x8 bf[4];
#pragma unroll
        for (int t = 0; t < 4; ++t) bf[t] = *(const f16x8*)(Bb + bro[t]);
        {
            f16x8 a0 = *(const f16x8*)(Ab + 0 * 1024 + arow);
            f16x8 a1 = *(const f16x8*)(Ab + 1 * 1024 + arow);
            f16x8 a2 = *(const f16x8*)(Ab + 2 * 1024 + arow);
            f16x8 a3 = *(const f16x8*)(Ab + 3 * 1024 + arow);
            PRIO(1);
#pragma unroll
            for (int t = 0; t < 4; ++t) {
                acc[0][t] = MFMA_F16(a0, bf[t], acc[0][t]);
                acc[1][t] = MFMA_F16(a1, bf[t], acc[1][t]);
                acc[2][t] = MFMA_F16(a2, bf[t], acc[2][t]);
                acc[3][t] = MFMA_F16(a3, bf[t], acc[3][t]);
            }
            PRIO(0);
        }
        BAR();
        // ---------- phase 1 ----------
        if (kt < 14) stageB(kt + 2, nbuf);
        {
            f16x8 a4 = *(const f16x8*)(Ab + 4 * 1024 + arow);
            f16x8 a5 = *(const f16x8*)(Ab + 5 * 1024 + arow);
            f16x8 a6 = *(const f16x8*)(Ab + 6 * 1024 + arow);
            f16x8 a7 = *(const f16x8*)(Ab + 7 * 1024 + arow);
            PRIO(1);
#pragma unroll
            for (int t = 0; t < 4; ++t) {
                acc[4][t] = MFMA_F16(a4, bf[t], acc[4][t]);
                acc[5][t] = MFMA_F16(a5, bf[t], acc[5][t]);
                acc[6][t] = MFMA_F16(a6, bf[t], acc[6][t]);
                acc[7][t] = MFMA_F16(a7, bf[t], acc[7][t]);
            }
            PRIO(0);
        }
        BAR();
    }

    // epilogue: bias + Cl(3,0) geometric product -> gp f16 in d_out
#pragma unroll
    for (int t = 0; t < 2; ++t) {
        const int ch = n0 + wn * 32 + t * 16 + r_lo;
        const float blv = bl_p[ch], brv = br_p[ch];
#pragma unroll
        for (int rr = 0; rr < 4; ++rr) {
            const int b_g = b0 + wb * 16 + s_hi * 4 + rr;
            float Lv[8], Rv[8];
#pragma unroll
            for (int i = 0; i < 8; ++i) { Lv[i] = acc[i][t][rr]; Rv[i] = acc[i][2 + t][rr]; }
            Lv[0] += blv; Rv[0] += brv;
            float g[8];
            g[0] = Lv[0]*Rv[0]+Lv[1]*Rv[1]+Lv[2]*Rv[2]+Lv[3]*Rv[3]-Lv[4]*Rv[4]-Lv[5]*Rv[5]-Lv[6]*Rv[6]-Lv[7]*Rv[7];
            g[1] = Lv[0]*Rv[1]+Lv[1]*Rv[0]-Lv[2]*Rv[4]-Lv[3]*Rv[5]+Lv[4]*Rv[2]+Lv[5]*Rv[3]-Lv[6]*Rv[7]-Lv[7]*Rv[6];
            g[2] = Lv[0]*Rv[2]+Lv[1]*Rv[4]+Lv[2]*Rv[0]-Lv[3]*Rv[6]-Lv[4]*Rv[1]+Lv[5]*Rv[7]+Lv[6]*Rv[3]+Lv[7]*Rv[5];
            g[3] = Lv[0]*Rv[3]+Lv[1]*Rv[5]+Lv[2]*Rv[6]+Lv[3]*Rv[0]-Lv[4]*Rv[7]-Lv[5]*Rv[1]-Lv[6]*Rv[2]-Lv[7]*Rv[4];
            g[4] = Lv[0]*Rv[4]+Lv[1]*Rv[2]-Lv[2]*Rv[1]+Lv[3]*Rv[7]+Lv[4]*Rv[0]-Lv[5]*Rv[6]+Lv[6]*Rv[5]+Lv[7]*Rv[3];
            g[5] = Lv[0]*Rv[5]+Lv[1]*Rv[3]-Lv[2]*Rv[7]-Lv[3]*Rv[1]+Lv[4]*Rv[6]+Lv[5]*Rv[0]-Lv[6]*Rv[4]-Lv[7]*Rv[2];
            g[6] = Lv[0]*Rv[6]+Lv[1]*Rv[7]+Lv[2]*Rv[3]-Lv[3]*Rv[2]-Lv[4]*Rv[5]+Lv[5]*Rv[4]+Lv[6]*Rv[0]+Lv[7]*Rv[1];
            g[7] = Lv[0]*Rv[7]+Lv[1]*Rv[6]-Lv[2]*Rv[5]+Lv[3]*Rv[4]+Lv[4]*Rv[3]-Lv[5]*Rv[2]+Lv[6]*Rv[1]+Lv[7]*Rv[0];
            char* dst = gp_out + (size_t)b_g * 16384 + (size_t)ch * 2;
#pragma unroll
            for (int i = 0; i < 8; ++i) *(f16*)(dst + (size_t)i * 1024) = (f16)g[i];
        }
    }
}

// ---------------------------------------------------------------------------
// k2 (R8-benched): block 16b x 512ch (norm intra-block), 512 thr / 8 waves,
// wave = 16b x 64ch (acc[8][4]); gp from d_out, 3 bufs, 2-phase, waits 7/5/0.
// Reads gp only from its own batch regions; overwrites them fp32 after.
// ---------------------------------------------------------------------------
__global__ __launch_bounds__(512, 2) void k2(
    const char* gp_in, const f16* __restrict__ wo,
    const float* __restrict__ bo_p, const float* __restrict__ an_p,
    float* outp)
{
    __shared__ __align__(16) f16 AsF[3 * 4096];
    __shared__ __align__(16) f16 BsF[3 * 16384];
    __shared__ float red[16][8];

    const int b0 = blockIdx.x * 16;
    const int tid = threadIdx.x, lane = tid & 63, wv = tid >> 6;
    const int r_lo = lane & 15, s_hi = lane >> 4;

    const int abl = tid >> 6, arw = (tid >> 2) & 15, agp = (tid & 3) ^ SWZ(arw);
    const char* aS = gp_in + (size_t)(b0 + arw) * 16384 + (size_t)abl * 1024 + agp * 16;
    const f16* bS[4];
#pragma unroll
    for (int j = 0; j < 4; ++j) {
        const int n = j * 128 + (tid >> 2);
        bS[j] = wo + (size_t)n * 512 + ((tid & 3) ^ SWZ(n)) * 8;
    }

    const int aoff = r_lo * 32 + ((s_hi ^ SWZ(r_lo)) << 3);
    int bro[4];
#pragma unroll
    for (int t = 0; t < 4; ++t) {
        const int nrow = wv * 64 + t * 16 + r_lo;
        bro[t] = nrow * 32 + ((s_hi ^ SWZ(nrow)) << 3);
    }

    f32x4 acc[8][4];
    const f32x4 zero = {0.f, 0.f, 0.f, 0.f};
#pragma unroll
    for (int i = 0; i < 8; ++i)
#pragma unroll
        for (int t = 0; t < 4; ++t) acc[i][t] = zero;

    auto stageB01 = [&](int kt, int buf) {
        GL2LDS(bS[0] + kt * 32, BsF + buf * 16384 + 0 * 4096 + wv * 512);
        GL2LDS(bS[1] + kt * 32, BsF + buf * 16384 + 1 * 4096 + wv * 512);
    };
    auto stageAB23 = [&](int kt, int buf) {
        GL2LDS(aS + kt * 64, AsF + buf * 4096 + wv * 512);
        GL2LDS(bS[2] + kt * 32, BsF + buf * 16384 + 2 * 4096 + wv * 512);
        GL2LDS(bS[3] + kt * 32, BsF + buf * 16384 + 3 * 4096 + wv * 512);
    };

    stageB01(0, 0); stageAB23(0, 0);
    stageB01(1, 1); stageAB23(1, 1);

#pragma unroll
    for (int kt = 0; kt < 16; ++kt) {
        const int buf = kt % 3, nbuf = (kt + 2) % 3;
        const f16* Ab = AsF + buf * 4096;
        const f16* Bb = BsF + buf * 16384;
        if (kt < 14) stageB01(kt + 2, nbuf);
        if (kt <= 13)      { WAITV(7); }
        else if (kt == 14) { WAITV(5); }
        else               { WAITV(0); }
        BAR();
        f16x8 af[8];
#pragma unroll
        for (int i = 0; i < 8; ++i) af[i] = *(const f16x8*)(Ab + i * 512 + aoff);
        {
            f16x8 b0f = *(const f16x8*)(Bb + bro[0]);
            f16x8 b1f = *(const f16x8*)(Bb + bro[1]);
            PRIO(1);
#pragma unroll
            for (int i = 0; i < 8; ++i) {
                acc[i][0] = MFMA_F16(af[i], b0f, acc[i][0]);
                acc[i][1] = MFMA_F16(af[i], b1f, acc[i][1]);
            }
            PRIO(0);
        }
        BAR();
        if (kt < 14) stageAB23(kt + 2, nbuf);
        {
            f16x8 b2f = *(const f16x8*)(Bb + bro[2]);
            f16x8 b3f = *(const f16x8*)(Bb + bro[3]);
            PRIO(1);
#pragma unroll
            for (int i = 0; i < 8; ++i) {
                acc[i][2] = MFMA_F16(af[i], b2f, acc[i][2]);
                acc[i][3] = MFMA_F16(af[i], b3f, acc[i][3]);
            }
            PRIO(0);
        }
        BAR();
    }

    float bo_t[4], an_t[4];
#pragma unroll
    for (int t = 0; t < 4; ++t) {
        const int c = wv * 64 + t * 16 + r_lo;
        bo_t[t] = bo_p[c]; an_t[t] = an_p[c];
    }

    float partial[4];
#pragma unroll
    for (int rr = 0; rr < 4; ++rr) {
        float sum = 0.f;
#pragma unroll
        for (int t = 0; t < 4; ++t) {
            float o = acc[0][t][rr] + bo_t[t];
            float ss = o * o;
#pragma unroll
            for (int i = 1; i < 8; ++i) ss += acc[i][t][rr] * acc[i][t][rr];
            sum += sqrtf(ss);
        }
        partial[rr] = sum;
    }
#pragma unroll
    for (int off = 1; off < 16; off <<= 1)
#pragma unroll
        for (int rr = 0; rr < 4; ++rr) partial[rr] += __shfl_xor(partial[rr], off);
    if (r_lo == 0)
#pragma unroll
        for (int rr = 0; rr < 4; ++rr) red[s_hi * 4 + rr][wv] = partial[rr];
    __syncthreads();

#pragma unroll
    for (int rr = 0; rr < 4; ++rr) {
        float tot = 0.f;
#pragma unroll
        for (int w = 0; w < 8; ++w) tot += red[s_hi * 4 + rr][w];
        const float inv = 1.0f / (tot * (1.0f / 512.0f) + 1e-6f);
        const int b_g = b0 + s_hi * 4 + rr;
        float* dst = outp + (size_t)b_g * 4096;
#pragma unroll
        for (int t = 0; t < 4; ++t) {
            const float sc = an_t[t] * inv;
            const int c = wv * 64 + t * 16 + r_lo;
            f32x4 v0, v1;
            v0[0] = (acc[0][t][rr] + bo_t[t]) * sc;
            v0[1] = acc[1][t][rr] * sc; v0[2] = acc[2][t][rr] * sc; v0[3] = acc[3][t][rr] * sc;
            v1[0] = acc[4][t][rr] * sc; v1[1] = acc[5][t][rr] * sc;
            v1[2] = acc[6][t][rr] * sc; v1[3] = acc[7][t][rr] * sc;
            *(f32x4*)(dst + (size_t)c * 8) = v0;
            *(f32x4*)(dst + (size_t)c * 8 + 4) = v1;
        }
    }
}

// ---------------------------------------------------------------------------
extern "C" void kernel_launch(void* const* d_in, const int* in_sizes, int n_in,
                              void* d_out, int out_size, void* d_ws, size_t ws_size,
                              hipStream_t stream) {
    const float* x  = (const float*)d_in[0];
    const float* wl = (const float*)d_in[1];
    const float* bl = (const float*)d_in[2];
    const float* wr = (const float*)d_in[3];
    const float* br = (const float*)d_in[4];
    const float* wo = (const float*)d_in[5];
    const float* bo = (const float*)d_in[6];
    const float* an = (const float*)d_in[7];
    f16* wf = (f16*)d_ws;
    f16* xt = wf + (1 << 20);   // byte offset 2MB

    hipLaunchKernelGGL(k0, dim3(9216), dim3(256), 0, stream, x, wl, wr, wo, wf, xt);
    hipLaunchKernelGGL(k1, dim3(2048), dim3(512), 0, stream, xt, wf, bl, br, (char*)d_out);
    hipLaunchKernelGGL(k2, dim3(1024), dim3(512), 0, stream,
                       (const char*)d_out, wf + 524288, bo, an, (float*)d_out);
}